// Round 5
// baseline (74.197 us; speedup 1.0000x reference)
//
#include <hip/hip_runtime.h>

#define BATCH 128
#define LEN 512
#define NCHUNK 4
#define CH_STEPS 128          // 4*128 = 512 >= 511; last chunk has 1 zero-pad step
#define STEPS_TOTAL 511
#define SIG_DIM 4680          // 8 + 64 + 512 + 4096
#define N_OUT 10
#define OFF2 8
#define OFF3 72
#define OFF4 584

// select dx[s][n] from the two loaded float4s by 3-bit per-lane index n.
// Compiles to 7 v_cndmask with loop-invariant masks hoisted into SGPR pairs.
__device__ __forceinline__ float sel8(const float4& a, const float4& b, int n) {
    const float lo = (n & 2) ? ((n & 1) ? a.w : a.z) : ((n & 1) ? a.y : a.x);
    const float hi = (n & 2) ? ((n & 1) ? b.w : b.z) : ((n & 1) ? b.y : b.x);
    return (n & 4) ? hi : lo;
}

// ---------------------------------------------------------------------------
// Per-wave scan body. H = wave index (compile-time): this wave's threads own
// k in {4H..4H+3}, so vk's are static components of va/vb (zero select cost).
// Thread t owns (i,j) = ((t>>3)&7, t&7) and 4 k's: state s3[4], s4[4][8].
// Per step: 2 broadcast ds_read_b128 + ~64 VALU covering 4 (i,j,k) tuples.
// ---------------------------------------------------------------------------
template <int H>
__device__ __forceinline__ void scan_and_store(const float4* __restrict__ dx4,
                                               float* __restrict__ o, int t) {
    const int i = (t >> 3) & 7, j = t & 7;
    float s1v = 0.f, s2v = 0.f;
    float s3[4] = {0.f, 0.f, 0.f, 0.f};
    float s4[4][8] = {};

    #pragma unroll 4
    for (int s = 0; s < CH_STEPS; ++s) {
        const float4 va = dx4[s * 2];
        const float4 vb = dx4[s * 2 + 1];
        const float vi = sel8(va, vb, i);
        const float vj = sel8(va, vb, j);
        const float vk[4] = {H ? vb.x : va.x, H ? vb.y : va.y,
                             H ? vb.z : va.z, H ? vb.w : va.w};
        const float vv[8] = {va.x, va.y, va.z, va.w, vb.x, vb.y, vb.z, vb.w};

        const float t1 = s1v * vj;
        const float p  = vi * vj;
        // u = s2/2 + t1/6 + p/24 ; w = s2 + t1/2 + p/6   (old state)
        const float u = fmaf(1.f / 24.f, p, fmaf(1.f / 6.f, t1, 0.5f * s2v));
        const float w = fmaf(1.f / 6.f, p, fmaf(0.5f, t1, s2v));

        #pragma unroll
        for (int m = 0; m < 4; ++m) {
            const float c0 = fmaf(vk[m], u, s3[m]);     // level-4 coefficient
            #pragma unroll
            for (int l = 0; l < 8; ++l)
                s4[m][l] = fmaf(c0, vv[l], s4[m][l]);
            s3[m] = fmaf(vk[m], w, s3[m]);
        }
        s2v = fmaf(0.5f, p, s2v + t1);
        s1v += vi;
    }

    if (H == 0) {
        if ((t & 7) == 0) o[(t >> 3) & 7] = s1v;        // s1[i], j==0 canonical
        o[OFF2 + (t & 63)] = s2v;                       // s2[i*8+j]
    }
    const int ij = t & 63;                              // i*8 + j
    *(float4*)&o[OFF3 + ij * 8 + H * 4] = make_float4(s3[0], s3[1], s3[2], s3[3]);
    #pragma unroll
    for (int m = 0; m < 4; ++m) {
        float* dst = &o[OFF4 + (size_t)(ij * 8 + H * 4 + m) * 8];
        *(float4*)dst       = make_float4(s4[m][0], s4[m][1], s4[m][2], s4[m][3]);
        *(float4*)(dst + 4) = make_float4(s4[m][4], s4[m][5], s4[m][6], s4[m][7]);
    }
}

// ---------------------------------------------------------------------------
// Kernel 1: per-(batch, chunk) depth-4 signature via Chen scan.
// 128 threads (2 waves). Stages dx (with the X[s+1]-X[s] diff) into LDS, then
// runs the fat-thread scan. 512 blocks -> 2 blocks/CU, 1 wave/SIMD.
// ---------------------------------------------------------------------------
__global__ __launch_bounds__(128) void sig_chunk_kernel(const float* __restrict__ X,
                                                        float* __restrict__ sig) {
    const int wg = blockIdx.x;          // b * NCHUNK + ch
    const int b  = wg >> 2;
    const int ch = wg & 3;
    const int s0 = ch * CH_STEPS;
    const int nst = min(CH_STEPS, STEPS_TOTAL - s0);
    const int t = threadIdx.x;

    __shared__ __align__(16) float4 dx4[CH_STEPS * 2];   // 4 KB
    const float4* __restrict__ Xb4 =
        (const float4*)(X + ((size_t)b * LEN + s0) * 8);
    #pragma unroll
    for (int q = t; q < CH_STEPS * 2; q += 128) {
        float4 d = make_float4(0.f, 0.f, 0.f, 0.f);
        if (q < nst * 2) {
            const float4 a = Xb4[q], c = Xb4[q + 2];
            d = make_float4(c.x - a.x, c.y - a.y, c.z - a.z, c.w - a.w);
        }
        dx4[q] = d;
    }
    __syncthreads();

    float* __restrict__ o = sig + (size_t)wg * SIG_DIM;
    if (t < 64) scan_and_store<0>(dx4, o, t);
    else        scan_and_store<1>(dx4, o, t);
}

// ---------------------------------------------------------------------------
// Kernel 2: per-batch Chen-combine of the NCHUNK chunk signatures + fused
// linear layer (sig @ W.T + b) with block reduction. (unchanged, verified)
// ---------------------------------------------------------------------------
#define SIG_V4 1170            // SIG_DIM / 4

__global__ __launch_bounds__(512) void sig_combine_linear(const float* __restrict__ ws,
                                                          const float* __restrict__ W,
                                                          const float* __restrict__ bias,
                                                          float* __restrict__ out) {
    const int b = blockIdx.x;
    const int t = threadIdx.x;
    const int i = t >> 6, j = (t >> 3) & 7, k = t & 7;
    const float* __restrict__ base = ws + (size_t)b * NCHUNK * SIG_DIM;

    // A := chunk 0 signature (per-thread ownership as in kernel 1's flat layout)
    float A1 = base[i];
    float A2 = base[OFF2 + i * 8 + j];
    float A3 = base[OFF3 + t];
    const float4 a4a = *(const float4*)&base[OFF4 + t * 8];
    const float4 a4b = *(const float4*)&base[OFF4 + t * 8 + 4];
    float A4[8] = {a4a.x, a4a.y, a4a.z, a4a.w, a4b.x, a4b.y, a4b.z, a4b.w};

    __shared__ __align__(16) float Bs[SIG_DIM];

    // prefetch chunk 1 into registers
    float4 pre[3];
    {
        const float4* __restrict__ cp4 = (const float4*)(base + SIG_DIM);
        #pragma unroll
        for (int q = 0; q < 3; ++q) {
            const int idx = t + q * 512;
            if (idx < SIG_V4) pre[q] = cp4[idx];
        }
    }

    for (int c = 1; c < NCHUNK; ++c) {
        __syncthreads();                    // previous combine done reading Bs
        #pragma unroll
        for (int q = 0; q < 3; ++q) {
            const int idx = t + q * 512;
            if (idx < SIG_V4) ((float4*)Bs)[idx] = pre[q];
        }
        __syncthreads();

        if (c + 1 < NCHUNK) {               // issue next chunk's loads now
            const float4* __restrict__ cp4 =
                (const float4*)(base + (size_t)(c + 1) * SIG_DIM);
            #pragma unroll
            for (int q = 0; q < 3; ++q) {
                const int idx = t + q * 512;
                if (idx < SIG_V4) pre[q] = cp4[idx];
            }
        }

        const float B1i = Bs[i], B1j = Bs[j], B1k = Bs[k];
        const float4 b1a = *(const float4*)&Bs[0];
        const float4 b1b = *(const float4*)&Bs[4];
        const float B2ij = Bs[OFF2 + i * 8 + j];
        const float B2jk = Bs[OFF2 + j * 8 + k];
        const float4 b2a = *(const float4*)&Bs[OFF2 + k * 8];
        const float4 b2b = *(const float4*)&Bs[OFF2 + k * 8 + 4];
        const float B3ijk = Bs[OFF3 + t];
        const float4 b3a = *(const float4*)&Bs[OFF3 + (j * 8 + k) * 8];
        const float4 b3b = *(const float4*)&Bs[OFF3 + (j * 8 + k) * 8 + 4];
        const float4 b4a = *(const float4*)&Bs[OFF4 + t * 8];
        const float4 b4b = *(const float4*)&Bs[OFF4 + t * 8 + 4];

        // C4 = A4 + A3⊗B1 + A2⊗B2 + A1⊗B3 + B4   (old A1..A3)
        A4[0] += A3 * b1a.x + A2 * b2a.x + A1 * b3a.x + b4a.x;
        A4[1] += A3 * b1a.y + A2 * b2a.y + A1 * b3a.y + b4a.y;
        A4[2] += A3 * b1a.z + A2 * b2a.z + A1 * b3a.z + b4a.z;
        A4[3] += A3 * b1a.w + A2 * b2a.w + A1 * b3a.w + b4a.w;
        A4[4] += A3 * b1b.x + A2 * b2b.x + A1 * b3b.x + b4b.x;
        A4[5] += A3 * b1b.y + A2 * b2b.y + A1 * b3b.y + b4b.y;
        A4[6] += A3 * b1b.z + A2 * b2b.z + A1 * b3b.z + b4b.z;
        A4[7] += A3 * b1b.w + A2 * b2b.w + A1 * b3b.w + b4b.w;
        // C3 = A3 + A2⊗B1 + A1⊗B2 + B3
        A3 += A2 * B1k + A1 * B2jk + B3ijk;
        // C2 = A2 + A1⊗B1 + B2
        A2 += A1 * B1j + B2ij;
        // C1
        A1 += B1i;
    }

    // Fused linear: out[b][n] = sum_d sig[d] * W[n][d] + bias[n]
    float part[N_OUT];
    #pragma unroll
    for (int n = 0; n < N_OUT; ++n) {
        const float* __restrict__ Wn = W + (size_t)n * SIG_DIM;
        float p = A3 * Wn[OFF3 + t];
        const float4 w4a = *(const float4*)&Wn[OFF4 + t * 8];
        const float4 w4b = *(const float4*)&Wn[OFF4 + t * 8 + 4];
        p = fmaf(A4[0], w4a.x, p);
        p = fmaf(A4[1], w4a.y, p);
        p = fmaf(A4[2], w4a.z, p);
        p = fmaf(A4[3], w4a.w, p);
        p = fmaf(A4[4], w4b.x, p);
        p = fmaf(A4[5], w4b.y, p);
        p = fmaf(A4[6], w4b.z, p);
        p = fmaf(A4[7], w4b.w, p);
        if ((t & 7) == 0)  p = fmaf(A2, Wn[OFF2 + (t >> 3)], p);  // canonical s2 owner
        if ((t & 63) == 0) p = fmaf(A1, Wn[t >> 6], p);           // canonical s1 owner
        part[n] = p;
    }

    // wave reduce (64 lanes) then cross-wave via LDS
    #pragma unroll
    for (int n = 0; n < N_OUT; ++n) {
        #pragma unroll
        for (int off = 32; off > 0; off >>= 1)
            part[n] += __shfl_xor(part[n], off, 64);
    }
    __shared__ float red[8][N_OUT];
    const int wv = t >> 6, ln = t & 63;
    if (ln == 0) {
        #pragma unroll
        for (int n = 0; n < N_OUT; ++n) red[wv][n] = part[n];
    }
    __syncthreads();
    if (t < N_OUT) {
        float s = bias[t];
        #pragma unroll
        for (int w = 0; w < 8; ++w) s += red[w][t];
        out[b * N_OUT + t] = s;
    }
}

extern "C" void kernel_launch(void* const* d_in, const int* in_sizes, int n_in,
                              void* d_out, int out_size, void* d_ws, size_t ws_size,
                              hipStream_t stream) {
    const float* X    = (const float*)d_in[0];
    const float* W    = (const float*)d_in[1];
    const float* bias = (const float*)d_in[2];
    float* out = (float*)d_out;
    float* sig = (float*)d_ws;                 // NCHUNK*BATCH*SIG_DIM*4 ≈ 9.6 MB

    hipLaunchKernelGGL(sig_chunk_kernel, dim3(BATCH * NCHUNK), dim3(128), 0, stream, X, sig);
    hipLaunchKernelGGL(sig_combine_linear, dim3(BATCH), dim3(512), 0, stream, sig, W, bias, out);
}

// Round 6
// 50.554 us; speedup vs baseline: 1.4677x; 1.4677x over previous
//
#include <hip/hip_runtime.h>

#define BATCH 128
#define LEN 512
#define NCHUNK 4
#define CH_STEPS 128          // 4*128 = 512 >= 511; last chunk has 1 zero-pad step
#define STEPS_TOTAL 511
#define SIG_DIM 4680          // 8 + 64 + 512 + 4096
#define N_OUT 10
#define OFF2 8
#define OFF3 72
#define OFF4 584
#define DXG_ELEMS (BATCH * NCHUNK * CH_STEPS * 8)   // 524288 floats = 2 MB

__device__ __forceinline__ float rdlane(float v, int l) {
    return __int_as_float(__builtin_amdgcn_readlane(__float_as_int(v), l));
}

// ---------------------------------------------------------------------------
// Kernel 0 (verified R3): dx[b][s][0..7] = X[b][s+1]-X[b][s], 0 past the end.
// ---------------------------------------------------------------------------
__global__ __launch_bounds__(512) void dx_kernel(const float* __restrict__ X,
                                                 float* __restrict__ dxg) {
    const int gid = blockIdx.x * 512 + threadIdx.x;   // one thread per (b, sg)
    const int b = gid >> 9, sg = gid & 511;
    float4 d0 = make_float4(0.f, 0.f, 0.f, 0.f);
    float4 d1 = d0;
    if (sg < STEPS_TOTAL) {
        const float4* xp = (const float4*)(X + ((size_t)b * LEN + sg) * 8);
        const float4 a0 = xp[0], a1 = xp[1], c0 = xp[2], c1 = xp[3];
        d0 = make_float4(c0.x - a0.x, c0.y - a0.y, c0.z - a0.z, c0.w - a0.w);
        d1 = make_float4(c1.x - a1.x, c1.y - a1.y, c1.z - a1.z, c1.w - a1.w);
    }
    float4* o = (float4*)(dxg + (size_t)gid * 8);     // [b][ch][sl][8] contiguous
    o[0] = d0;
    o[1] = d1;
}

// ---------------------------------------------------------------------------
// Kernel 1: per-(batch, chunk) depth-4 signature via Chen scan.
// R0 ownership: thread t owns (i,j,k) = (t>>6, (t>>3)&7, t&7); i == wave id.
// dx lives in wave REGISTERS: lane (s&7)*8+c of phase-reg r=(s>>3)&3 holds
// dx[s][c]. Per step: 9 v_readlane (VALU broadcast -> SGPRs) + 2 ds_read_b32
// (vj, vk per-lane broadcast) + 19 FMA. LDS pipe ~10 us/CU, VALU ~12 us/SIMD.
// ---------------------------------------------------------------------------
__global__ __launch_bounds__(512) void sig_chunk_kernel(const float* __restrict__ dxg,
                                                        float* __restrict__ sig) {
    const int wg = blockIdx.x;          // b * NCHUNK + ch
    const int t = threadIdx.x;
    const int lane = t & 63;
    const int wv = t >> 6;              // == i, wave-uniform
    const int j = (t >> 3) & 7, k = t & 7;

    __shared__ __align__(8) float dxs[CH_STEPS * 8];   // 4 KB, for vj/vk reads
    const float* __restrict__ g = dxg + (size_t)wg * (CH_STEPS * 8);
    ((float2*)dxs)[t] = ((const float2*)g)[t];         // 512 x 8B = 4 KB
    __syncthreads();

    float s1v = 0.f, s2v = 0.f, s3v = 0.f;
    float s4v[8] = {0.f, 0.f, 0.f, 0.f, 0.f, 0.f, 0.f, 0.f};

    // phase 0 register load (coalesced 256B/instr)
    float c0r = g[lane], c1r = g[64 + lane], c2r = g[128 + lane], c3r = g[192 + lane];

    for (int ph = 0; ph < 4; ++ph) {                   // 4 phases x 32 steps
        float n0r = 0.f, n1r = 0.f, n2r = 0.f, n3r = 0.f;
        if (ph < 3) {                                  // prefetch next phase
            const float* __restrict__ gn = g + (ph + 1) * 256;
            n0r = gn[lane];  n1r = gn[64 + lane];
            n2r = gn[128 + lane];  n3r = gn[192 + lane];
        }
        const float* __restrict__ dphase = dxs + ph * 256;

        #pragma unroll
        for (int r = 0; r < 4; ++r) {
            const float dr = (r == 0) ? c0r : (r == 1) ? c1r : (r == 2) ? c2r : c3r;
            #pragma unroll
            for (int q = 0; q < 8; ++q) {
                const int sl = r * 8 + q;
                // block-uniform channel broadcasts -> SGPRs
                const float v0 = rdlane(dr, q * 8 + 0);
                const float v1 = rdlane(dr, q * 8 + 1);
                const float v2 = rdlane(dr, q * 8 + 2);
                const float v3 = rdlane(dr, q * 8 + 3);
                const float v4 = rdlane(dr, q * 8 + 4);
                const float v5 = rdlane(dr, q * 8 + 5);
                const float v6 = rdlane(dr, q * 8 + 6);
                const float v7 = rdlane(dr, q * 8 + 7);
                const float vi = rdlane(dr, q * 8 + wv);   // wave-uniform index
                const float vj = dphase[sl * 8 + j];       // LDS broadcast
                const float vk = dphase[sl * 8 + k];       // LDS broadcast

                const float t1 = s1v * vj;
                const float p  = vi * vj;
                // u = s2/2 + t1/6 + p/24 ; w = s2 + t1/2 + p/6   (old state)
                const float u  = fmaf(1.f / 24.f, p, fmaf(1.f / 6.f, t1, 0.5f * s2v));
                const float w  = fmaf(1.f / 6.f, p, fmaf(0.5f, t1, s2v));
                const float cc = fmaf(vk, u, s3v);         // level-4 coefficient
                s4v[0] = fmaf(cc, v0, s4v[0]);
                s4v[1] = fmaf(cc, v1, s4v[1]);
                s4v[2] = fmaf(cc, v2, s4v[2]);
                s4v[3] = fmaf(cc, v3, s4v[3]);
                s4v[4] = fmaf(cc, v4, s4v[4]);
                s4v[5] = fmaf(cc, v5, s4v[5]);
                s4v[6] = fmaf(cc, v6, s4v[6]);
                s4v[7] = fmaf(cc, v7, s4v[7]);
                s3v = fmaf(vk, w, s3v);
                s2v = fmaf(0.5f, p, s2v + t1);
                s1v += vi;
            }
        }
        c0r = n0r; c1r = n1r; c2r = n2r; c3r = n3r;
    }

    float* __restrict__ o = sig + (size_t)wg * SIG_DIM;
    if ((t & 63) == 0) o[t >> 6] = s1v;                // s1[i]
    if ((t & 7) == 0)  o[OFF2 + (t >> 3)] = s2v;       // s2[ij]
    o[OFF3 + t] = s3v;
    *(float4*)&o[OFF4 + t * 8]     = make_float4(s4v[0], s4v[1], s4v[2], s4v[3]);
    *(float4*)&o[OFF4 + t * 8 + 4] = make_float4(s4v[4], s4v[5], s4v[6], s4v[7]);
}

// ---------------------------------------------------------------------------
// Kernel 2 (verified): per-batch Chen-combine of the NCHUNK chunk signatures
// + fused linear layer (sig @ W.T + b) with block reduction.
// ---------------------------------------------------------------------------
#define SIG_V4 1170            // SIG_DIM / 4

__global__ __launch_bounds__(512) void sig_combine_linear(const float* __restrict__ ws,
                                                          const float* __restrict__ W,
                                                          const float* __restrict__ bias,
                                                          float* __restrict__ out) {
    const int b = blockIdx.x;
    const int t = threadIdx.x;
    const int i = t >> 6, j = (t >> 3) & 7, k = t & 7;
    const float* __restrict__ base = ws + (size_t)b * NCHUNK * SIG_DIM;

    // A := chunk 0 signature (per-thread ownership as in kernel 1)
    float A1 = base[i];
    float A2 = base[OFF2 + i * 8 + j];
    float A3 = base[OFF3 + t];
    const float4 a4a = *(const float4*)&base[OFF4 + t * 8];
    const float4 a4b = *(const float4*)&base[OFF4 + t * 8 + 4];
    float A4[8] = {a4a.x, a4a.y, a4a.z, a4a.w, a4b.x, a4b.y, a4b.z, a4b.w};

    __shared__ __align__(16) float Bs[SIG_DIM];

    // prefetch chunk 1 into registers
    float4 pre[3];
    {
        const float4* __restrict__ cp4 = (const float4*)(base + SIG_DIM);
        #pragma unroll
        for (int q = 0; q < 3; ++q) {
            const int idx = t + q * 512;
            if (idx < SIG_V4) pre[q] = cp4[idx];
        }
    }

    for (int c = 1; c < NCHUNK; ++c) {
        __syncthreads();                    // previous combine done reading Bs
        #pragma unroll
        for (int q = 0; q < 3; ++q) {
            const int idx = t + q * 512;
            if (idx < SIG_V4) ((float4*)Bs)[idx] = pre[q];
        }
        __syncthreads();

        if (c + 1 < NCHUNK) {               // issue next chunk's loads now
            const float4* __restrict__ cp4 =
                (const float4*)(base + (size_t)(c + 1) * SIG_DIM);
            #pragma unroll
            for (int q = 0; q < 3; ++q) {
                const int idx = t + q * 512;
                if (idx < SIG_V4) pre[q] = cp4[idx];
            }
        }

        const float B1i = Bs[i], B1j = Bs[j], B1k = Bs[k];
        const float4 b1a = *(const float4*)&Bs[0];
        const float4 b1b = *(const float4*)&Bs[4];
        const float B2ij = Bs[OFF2 + i * 8 + j];
        const float B2jk = Bs[OFF2 + j * 8 + k];
        const float4 b2a = *(const float4*)&Bs[OFF2 + k * 8];
        const float4 b2b = *(const float4*)&Bs[OFF2 + k * 8 + 4];
        const float B3ijk = Bs[OFF3 + t];
        const float4 b3a = *(const float4*)&Bs[OFF3 + (j * 8 + k) * 8];
        const float4 b3b = *(const float4*)&Bs[OFF3 + (j * 8 + k) * 8 + 4];
        const float4 b4a = *(const float4*)&Bs[OFF4 + t * 8];
        const float4 b4b = *(const float4*)&Bs[OFF4 + t * 8 + 4];

        // C4 = A4 + A3⊗B1 + A2⊗B2 + A1⊗B3 + B4   (old A1..A3)
        A4[0] += A3 * b1a.x + A2 * b2a.x + A1 * b3a.x + b4a.x;
        A4[1] += A3 * b1a.y + A2 * b2a.y + A1 * b3a.y + b4a.y;
        A4[2] += A3 * b1a.z + A2 * b2a.z + A1 * b3a.z + b4a.z;
        A4[3] += A3 * b1a.w + A2 * b2a.w + A1 * b3a.w + b4a.w;
        A4[4] += A3 * b1b.x + A2 * b2b.x + A1 * b3b.x + b4b.x;
        A4[5] += A3 * b1b.y + A2 * b2b.y + A1 * b3b.y + b4b.y;
        A4[6] += A3 * b1b.z + A2 * b2b.z + A1 * b3b.z + b4b.z;
        A4[7] += A3 * b1b.w + A2 * b2b.w + A1 * b3b.w + b4b.w;
        // C3 = A3 + A2⊗B1 + A1⊗B2 + B3
        A3 += A2 * B1k + A1 * B2jk + B3ijk;
        // C2 = A2 + A1⊗B1 + B2
        A2 += A1 * B1j + B2ij;
        // C1
        A1 += B1i;
    }

    // Fused linear: out[b][n] = sum_d sig[d] * W[n][d] + bias[n]
    float part[N_OUT];
    #pragma unroll
    for (int n = 0; n < N_OUT; ++n) {
        const float* __restrict__ Wn = W + (size_t)n * SIG_DIM;
        float p = A3 * Wn[OFF3 + t];
        const float4 w4a = *(const float4*)&Wn[OFF4 + t * 8];
        const float4 w4b = *(const float4*)&Wn[OFF4 + t * 8 + 4];
        p = fmaf(A4[0], w4a.x, p);
        p = fmaf(A4[1], w4a.y, p);
        p = fmaf(A4[2], w4a.z, p);
        p = fmaf(A4[3], w4a.w, p);
        p = fmaf(A4[4], w4b.x, p);
        p = fmaf(A4[5], w4b.y, p);
        p = fmaf(A4[6], w4b.z, p);
        p = fmaf(A4[7], w4b.w, p);
        if ((t & 7) == 0)  p = fmaf(A2, Wn[OFF2 + (t >> 3)], p);  // canonical s2 owner
        if ((t & 63) == 0) p = fmaf(A1, Wn[t >> 6], p);           // canonical s1 owner
        part[n] = p;
    }

    // wave reduce (64 lanes) then cross-wave via LDS
    #pragma unroll
    for (int n = 0; n < N_OUT; ++n) {
        #pragma unroll
        for (int off = 32; off > 0; off >>= 1)
            part[n] += __shfl_xor(part[n], off, 64);
    }
    __shared__ float red[8][N_OUT];
    const int wv = t >> 6, ln = t & 63;
    if (ln == 0) {
        #pragma unroll
        for (int n = 0; n < N_OUT; ++n) red[wv][n] = part[n];
    }
    __syncthreads();
    if (t < N_OUT) {
        float s = bias[t];
        #pragma unroll
        for (int w = 0; w < 8; ++w) s += red[w][t];
        out[b * N_OUT + t] = s;
    }
}

extern "C" void kernel_launch(void* const* d_in, const int* in_sizes, int n_in,
                              void* d_out, int out_size, void* d_ws, size_t ws_size,
                              hipStream_t stream) {
    const float* X    = (const float*)d_in[0];
    const float* W    = (const float*)d_in[1];
    const float* bias = (const float*)d_in[2];
    float* out = (float*)d_out;
    float* dxg = (float*)d_ws;                 // 2 MB
    float* sig = (float*)d_ws + DXG_ELEMS;     // 9.6 MB

    hipLaunchKernelGGL(dx_kernel, dim3(BATCH * LEN / 512), dim3(512), 0, stream, X, dxg);
    hipLaunchKernelGGL(sig_chunk_kernel, dim3(BATCH * NCHUNK), dim3(512), 0, stream, dxg, sig);
    hipLaunchKernelGGL(sig_combine_linear, dim3(BATCH), dim3(512), 0, stream, sig, W, bias, out);
}

// Round 7
// 41.334 us; speedup vs baseline: 1.7951x; 1.2230x over previous
//
#include <hip/hip_runtime.h>

#define BATCH 128
#define LEN 512
#define NCHUNK 4
#define CH_STEPS 128          // 4*128 = 512 >= 511; last chunk has 1 zero-pad step
#define STEPS_TOTAL 511
#define SIG_DIM 4680          // 8 + 64 + 512 + 4096
#define N_OUT 10
#define OFF2 8
#define OFF3 72
#define OFF4 584
#define DXG_ELEMS (BATCH * NCHUNK * CH_STEPS * 8)   // 524288 floats = 2 MB

typedef float v2f __attribute__((ext_vector_type(2)));

// ---------------------------------------------------------------------------
// Kernel 0 (verified R3/R4): dx[b][s][0..7] = X[b][s+1]-X[b][s], 0 past end.
// ---------------------------------------------------------------------------
__global__ __launch_bounds__(512) void dx_kernel(const float* __restrict__ X,
                                                 float* __restrict__ dxg) {
    const int gid = blockIdx.x * 512 + threadIdx.x;   // one thread per (b, sg)
    const int b = gid >> 9, sg = gid & 511;
    float4 d0 = make_float4(0.f, 0.f, 0.f, 0.f);
    float4 d1 = d0;
    if (sg < STEPS_TOTAL) {
        const float4* xp = (const float4*)(X + ((size_t)b * LEN + sg) * 8);
        const float4 a0 = xp[0], a1 = xp[1], c0 = xp[2], c1 = xp[3];
        d0 = make_float4(c0.x - a0.x, c0.y - a0.y, c0.z - a0.z, c0.w - a0.w);
        d1 = make_float4(c1.x - a1.x, c1.y - a1.y, c1.z - a1.z, c1.w - a1.w);
    }
    float4* o = (float4*)(dxg + (size_t)gid * 8);     // [b][ch][sl][8] contiguous
    o[0] = d0;
    o[1] = d1;
}

// ---------------------------------------------------------------------------
// Per-wave scan body, WV = wave index (compile-time). Pipe split per step:
//   va/vb: 2x VMEM float4 broadcast (uniform addr, L1)   ~8  VMEM-cyc/wave
//   vj,vk: 2x ds_read_b32 broadcast (8 distinct addrs)   ~12 LDS-cyc/wave
//   vi   : compile-time component of va/vb (WV)           0
//   s4   : 4x v_pk_fma_f32 + ~9 scalar VALU              ~13 instr/step
// ---------------------------------------------------------------------------
template <int WV>
__device__ __forceinline__ void scan_body(const float4* __restrict__ g4,
                                          const float* __restrict__ dxs,
                                          float* __restrict__ o, int t) {
    const int j = (t >> 3) & 7, k = t & 7;
    float s1v = 0.f, s2v = 0.f, s3v = 0.f;
    v2f s4[4] = {{0.f, 0.f}, {0.f, 0.f}, {0.f, 0.f}, {0.f, 0.f}};

    #pragma unroll 4
    for (int s = 0; s < CH_STEPS; ++s) {
        const float4 va = g4[s * 2];          // VMEM broadcast (block-uniform)
        const float4 vb = g4[s * 2 + 1];
        const float vi = (WV == 0) ? va.x : (WV == 1) ? va.y : (WV == 2) ? va.z :
                         (WV == 3) ? va.w : (WV == 4) ? vb.x : (WV == 5) ? vb.y :
                         (WV == 6) ? vb.z : vb.w;
        const float vj = dxs[s * 8 + j];      // LDS broadcast
        const float vk = dxs[s * 8 + k];      // LDS broadcast

        const float t1 = s1v * vj;
        const float p  = vi * vj;
        // u = s2/2 + t1/6 + p/24 ; w = s2 + t1/2 + p/6   (old state)
        const float u  = fmaf(1.f / 24.f, p, fmaf(1.f / 6.f, t1, 0.5f * s2v));
        const float w  = fmaf(1.f / 6.f, p, fmaf(0.5f, t1, s2v));
        const float cc = fmaf(vk, u, s3v);    // level-4 coefficient
        const v2f c2 = {cc, cc};
        s4[0] = __builtin_elementwise_fma(c2, (v2f){va.x, va.y}, s4[0]);
        s4[1] = __builtin_elementwise_fma(c2, (v2f){va.z, va.w}, s4[1]);
        s4[2] = __builtin_elementwise_fma(c2, (v2f){vb.x, vb.y}, s4[2]);
        s4[3] = __builtin_elementwise_fma(c2, (v2f){vb.z, vb.w}, s4[3]);
        s3v = fmaf(vk, w, s3v);
        s2v = fmaf(0.5f, p, s2v + t1);
        s1v += vi;
    }

    if ((t & 63) == 0) o[WV] = s1v;                    // s1[i], i == WV
    if ((t & 7) == 0)  o[OFF2 + (t >> 3)] = s2v;       // s2[ij]
    o[OFF3 + t] = s3v;
    *(float4*)&o[OFF4 + t * 8]     = make_float4(s4[0].x, s4[0].y, s4[1].x, s4[1].y);
    *(float4*)&o[OFF4 + t * 8 + 4] = make_float4(s4[2].x, s4[2].y, s4[3].x, s4[3].y);
}

// ---------------------------------------------------------------------------
// Kernel 1: per-(batch, chunk) depth-4 signature via Chen scan.
// R0 ownership: thread t owns (i,j,k) = (t>>6, (t>>3)&7, t&7); i == wave id.
// 512 blocks x 512 threads -> 2 blocks/CU, 16 waves/CU, 4 waves/SIMD.
// ---------------------------------------------------------------------------
__global__ __launch_bounds__(512) void sig_chunk_kernel(const float* __restrict__ dxg,
                                                        float* __restrict__ sig) {
    const int wg = blockIdx.x;          // b * NCHUNK + ch
    const int t = threadIdx.x;

    __shared__ __align__(16) float dxs[CH_STEPS * 8];  // 4 KB, for vj/vk reads
    const float* __restrict__ g = dxg + (size_t)wg * (CH_STEPS * 8);
    ((float2*)dxs)[t] = ((const float2*)g)[t];         // 512 x 8B = 4 KB
    __syncthreads();

    float* __restrict__ o = sig + (size_t)wg * SIG_DIM;
    const float4* __restrict__ g4 = (const float4*)g;
    switch (t >> 6) {
        case 0: scan_body<0>(g4, dxs, o, t); break;
        case 1: scan_body<1>(g4, dxs, o, t); break;
        case 2: scan_body<2>(g4, dxs, o, t); break;
        case 3: scan_body<3>(g4, dxs, o, t); break;
        case 4: scan_body<4>(g4, dxs, o, t); break;
        case 5: scan_body<5>(g4, dxs, o, t); break;
        case 6: scan_body<6>(g4, dxs, o, t); break;
        default: scan_body<7>(g4, dxs, o, t); break;
    }
}

// ---------------------------------------------------------------------------
// Kernel 2 (verified): per-batch Chen-combine of the NCHUNK chunk signatures
// + fused linear layer (sig @ W.T + b) with block reduction.
// ---------------------------------------------------------------------------
#define SIG_V4 1170            // SIG_DIM / 4

__global__ __launch_bounds__(512) void sig_combine_linear(const float* __restrict__ ws,
                                                          const float* __restrict__ W,
                                                          const float* __restrict__ bias,
                                                          float* __restrict__ out) {
    const int b = blockIdx.x;
    const int t = threadIdx.x;
    const int i = t >> 6, j = (t >> 3) & 7, k = t & 7;
    const float* __restrict__ base = ws + (size_t)b * NCHUNK * SIG_DIM;

    // A := chunk 0 signature (per-thread ownership as in kernel 1)
    float A1 = base[i];
    float A2 = base[OFF2 + i * 8 + j];
    float A3 = base[OFF3 + t];
    const float4 a4a = *(const float4*)&base[OFF4 + t * 8];
    const float4 a4b = *(const float4*)&base[OFF4 + t * 8 + 4];
    float A4[8] = {a4a.x, a4a.y, a4a.z, a4a.w, a4b.x, a4b.y, a4b.z, a4b.w};

    __shared__ __align__(16) float Bs[SIG_DIM];

    // prefetch chunk 1 into registers
    float4 pre[3];
    {
        const float4* __restrict__ cp4 = (const float4*)(base + SIG_DIM);
        #pragma unroll
        for (int q = 0; q < 3; ++q) {
            const int idx = t + q * 512;
            if (idx < SIG_V4) pre[q] = cp4[idx];
        }
    }

    for (int c = 1; c < NCHUNK; ++c) {
        __syncthreads();                    // previous combine done reading Bs
        #pragma unroll
        for (int q = 0; q < 3; ++q) {
            const int idx = t + q * 512;
            if (idx < SIG_V4) ((float4*)Bs)[idx] = pre[q];
        }
        __syncthreads();

        if (c + 1 < NCHUNK) {               // issue next chunk's loads now
            const float4* __restrict__ cp4 =
                (const float4*)(base + (size_t)(c + 1) * SIG_DIM);
            #pragma unroll
            for (int q = 0; q < 3; ++q) {
                const int idx = t + q * 512;
                if (idx < SIG_V4) pre[q] = cp4[idx];
            }
        }

        const float B1i = Bs[i], B1j = Bs[j], B1k = Bs[k];
        const float4 b1a = *(const float4*)&Bs[0];
        const float4 b1b = *(const float4*)&Bs[4];
        const float B2ij = Bs[OFF2 + i * 8 + j];
        const float B2jk = Bs[OFF2 + j * 8 + k];
        const float4 b2a = *(const float4*)&Bs[OFF2 + k * 8];
        const float4 b2b = *(const float4*)&Bs[OFF2 + k * 8 + 4];
        const float B3ijk = Bs[OFF3 + t];
        const float4 b3a = *(const float4*)&Bs[OFF3 + (j * 8 + k) * 8];
        const float4 b3b = *(const float4*)&Bs[OFF3 + (j * 8 + k) * 8 + 4];
        const float4 b4a = *(const float4*)&Bs[OFF4 + t * 8];
        const float4 b4b = *(const float4*)&Bs[OFF4 + t * 8 + 4];

        // C4 = A4 + A3⊗B1 + A2⊗B2 + A1⊗B3 + B4   (old A1..A3)
        A4[0] += A3 * b1a.x + A2 * b2a.x + A1 * b3a.x + b4a.x;
        A4[1] += A3 * b1a.y + A2 * b2a.y + A1 * b3a.y + b4a.y;
        A4[2] += A3 * b1a.z + A2 * b2a.z + A1 * b3a.z + b4a.z;
        A4[3] += A3 * b1a.w + A2 * b2a.w + A1 * b3a.w + b4a.w;
        A4[4] += A3 * b1b.x + A2 * b2b.x + A1 * b3b.x + b4b.x;
        A4[5] += A3 * b1b.y + A2 * b2b.y + A1 * b3b.y + b4b.y;
        A4[6] += A3 * b1b.z + A2 * b2b.z + A1 * b3b.z + b4b.z;
        A4[7] += A3 * b1b.w + A2 * b2b.w + A1 * b3b.w + b4b.w;
        // C3 = A3 + A2⊗B1 + A1⊗B2 + B3
        A3 += A2 * B1k + A1 * B2jk + B3ijk;
        // C2 = A2 + A1⊗B1 + B2
        A2 += A1 * B1j + B2ij;
        // C1
        A1 += B1i;
    }

    // Fused linear: out[b][n] = sum_d sig[d] * W[n][d] + bias[n]
    float part[N_OUT];
    #pragma unroll
    for (int n = 0; n < N_OUT; ++n) {
        const float* __restrict__ Wn = W + (size_t)n * SIG_DIM;
        float p = A3 * Wn[OFF3 + t];
        const float4 w4a = *(const float4*)&Wn[OFF4 + t * 8];
        const float4 w4b = *(const float4*)&Wn[OFF4 + t * 8 + 4];
        p = fmaf(A4[0], w4a.x, p);
        p = fmaf(A4[1], w4a.y, p);
        p = fmaf(A4[2], w4a.z, p);
        p = fmaf(A4[3], w4a.w, p);
        p = fmaf(A4[4], w4b.x, p);
        p = fmaf(A4[5], w4b.y, p);
        p = fmaf(A4[6], w4b.z, p);
        p = fmaf(A4[7], w4b.w, p);
        if ((t & 7) == 0)  p = fmaf(A2, Wn[OFF2 + (t >> 3)], p);  // canonical s2 owner
        if ((t & 63) == 0) p = fmaf(A1, Wn[t >> 6], p);           // canonical s1 owner
        part[n] = p;
    }

    // wave reduce (64 lanes) then cross-wave via LDS
    #pragma unroll
    for (int n = 0; n < N_OUT; ++n) {
        #pragma unroll
        for (int off = 32; off > 0; off >>= 1)
            part[n] += __shfl_xor(part[n], off, 64);
    }
    __shared__ float red[8][N_OUT];
    const int wv = t >> 6, ln = t & 63;
    if (ln == 0) {
        #pragma unroll
        for (int n = 0; n < N_OUT; ++n) red[wv][n] = part[n];
    }
    __syncthreads();
    if (t < N_OUT) {
        float s = bias[t];
        #pragma unroll
        for (int w = 0; w < 8; ++w) s += red[w][t];
        out[b * N_OUT + t] = s;
    }
}

extern "C" void kernel_launch(void* const* d_in, const int* in_sizes, int n_in,
                              void* d_out, int out_size, void* d_ws, size_t ws_size,
                              hipStream_t stream) {
    const float* X    = (const float*)d_in[0];
    const float* W    = (const float*)d_in[1];
    const float* bias = (const float*)d_in[2];
    float* out = (float*)d_out;
    float* dxg = (float*)d_ws;                 // 2 MB
    float* sig = (float*)d_ws + DXG_ELEMS;     // 9.6 MB

    hipLaunchKernelGGL(dx_kernel, dim3(BATCH * LEN / 512), dim3(512), 0, stream, X, dxg);
    hipLaunchKernelGGL(sig_chunk_kernel, dim3(BATCH * NCHUNK), dim3(512), 0, stream, dxg, sig);
    hipLaunchKernelGGL(sig_combine_linear, dim3(BATCH), dim3(512), 0, stream, sig, W, bias, out);
}

// Round 8
// 41.240 us; speedup vs baseline: 1.7992x; 1.0023x over previous
//
#include <hip/hip_runtime.h>

#define BATCH 128
#define LEN 512
#define NCHUNK 2
#define CH_STEPS 256          // chunk0: 256 steps, chunk1: 255 steps (no pad)
#define STEPS_TOTAL 511
#define SIG_DIM 4680          // 8 + 64 + 512 + 4096
#define N_OUT 10
#define OFF2 8
#define OFF3 72
#define OFF4 584

typedef float v2f __attribute__((ext_vector_type(2)));

// ---------------------------------------------------------------------------
// Per-wave scan body. WV = wave index (compile-time) = owned i; NST = step
// count (256 for chunk0, 255 for chunk1 -- the pad step is skipped, a zero
// increment is the identity). Pipe split per step:
//   X[s+1]: 2x uniform VMEM float4 (L1-resident 8KB)   ~8  VMEM-cyc/wave
//   dx    : 4x v_pk_sub from prev-register pipeline
//   vj,vk : 2x ds_read_b32 broadcast (8 distinct addrs) ~12 LDS-cyc/wave
//   vi    : compile-time component of dx (WV)             0
//   s4    : 4x v_pk_fma + ~9 scalar VALU
// ---------------------------------------------------------------------------
template <int WV, int NST>
__device__ __forceinline__ void scan_body(const float4* __restrict__ Xf4, int s0,
                                          const float* __restrict__ dxs,
                                          float* __restrict__ o, int t) {
    const int j = (t >> 3) & 7, k = t & 7;
    float s1v = 0.f, s2v = 0.f, s3v = 0.f;
    v2f s4[4] = {{0.f, 0.f}, {0.f, 0.f}, {0.f, 0.f}, {0.f, 0.f}};

    v2f p0, p1, p2, p3;
    {
        const float4 pA = Xf4[s0 * 2], pB = Xf4[s0 * 2 + 1];
        p0 = (v2f){pA.x, pA.y}; p1 = (v2f){pA.z, pA.w};
        p2 = (v2f){pB.x, pB.y}; p3 = (v2f){pB.z, pB.w};
    }

    #pragma unroll 4
    for (int s = 0; s < NST; ++s) {
        const float4 cA = Xf4[(s0 + s + 1) * 2];      // uniform VMEM broadcast
        const float4 cB = Xf4[(s0 + s + 1) * 2 + 1];
        const v2f c0 = (v2f){cA.x, cA.y}, c1 = (v2f){cA.z, cA.w};
        const v2f c2 = (v2f){cB.x, cB.y}, c3 = (v2f){cB.z, cB.w};
        const v2f d0 = c0 - p0, d1 = c1 - p1, d2 = c2 - p2, d3 = c3 - p3;
        p0 = c0; p1 = c1; p2 = c2; p3 = c3;

        const float vi = (WV == 0) ? d0.x : (WV == 1) ? d0.y : (WV == 2) ? d1.x :
                         (WV == 3) ? d1.y : (WV == 4) ? d2.x : (WV == 5) ? d2.y :
                         (WV == 6) ? d3.x : d3.y;
        const float vj = dxs[s * 8 + j];              // LDS broadcast
        const float vk = dxs[s * 8 + k];              // LDS broadcast

        const float t1 = s1v * vj;
        const float p  = vi * vj;
        // u = s2/2 + t1/6 + p/24 ; w = s2 + t1/2 + p/6   (old state)
        const float u  = fmaf(1.f / 24.f, p, fmaf(1.f / 6.f, t1, 0.5f * s2v));
        const float w  = fmaf(1.f / 6.f, p, fmaf(0.5f, t1, s2v));
        const float cc = fmaf(vk, u, s3v);            // level-4 coefficient
        const v2f cc2 = {cc, cc};
        s4[0] = __builtin_elementwise_fma(cc2, d0, s4[0]);
        s4[1] = __builtin_elementwise_fma(cc2, d1, s4[1]);
        s4[2] = __builtin_elementwise_fma(cc2, d2, s4[2]);
        s4[3] = __builtin_elementwise_fma(cc2, d3, s4[3]);
        s3v = fmaf(vk, w, s3v);
        s2v = fmaf(0.5f, p, s2v + t1);
        s1v += vi;
    }

    if ((t & 63) == 0) o[WV] = s1v;                    // s1[i], i == WV
    if ((t & 7) == 0)  o[OFF2 + (t >> 3)] = s2v;       // s2[ij]
    o[OFF3 + t] = s3v;
    *(float4*)&o[OFF4 + t * 8]     = make_float4(s4[0].x, s4[0].y, s4[1].x, s4[1].y);
    *(float4*)&o[OFF4 + t * 8 + 4] = make_float4(s4[2].x, s4[2].y, s4[3].x, s4[3].y);
}

template <int NST>
__device__ __forceinline__ void scan_dispatch(const float4* __restrict__ Xf4, int s0,
                                              const float* __restrict__ dxs,
                                              float* __restrict__ o, int t) {
    switch (t >> 6) {
        case 0: scan_body<0, NST>(Xf4, s0, dxs, o, t); break;
        case 1: scan_body<1, NST>(Xf4, s0, dxs, o, t); break;
        case 2: scan_body<2, NST>(Xf4, s0, dxs, o, t); break;
        case 3: scan_body<3, NST>(Xf4, s0, dxs, o, t); break;
        case 4: scan_body<4, NST>(Xf4, s0, dxs, o, t); break;
        case 5: scan_body<5, NST>(Xf4, s0, dxs, o, t); break;
        case 6: scan_body<6, NST>(Xf4, s0, dxs, o, t); break;
        default: scan_body<7, NST>(Xf4, s0, dxs, o, t); break;
    }
}

// ---------------------------------------------------------------------------
// Kernel 1: per-(batch, half) depth-4 signature via Chen scan.
// Thread t owns (i,j,k) = (t>>6, (t>>3)&7, t&7); i == wave id.
// 256 blocks x 512 threads = exactly 1 block/CU, 2 waves/SIMD.
// dx computed from X during LDS staging (no dx kernel, no global dx).
// ---------------------------------------------------------------------------
__global__ __launch_bounds__(512) void sig_chunk_kernel(const float* __restrict__ X,
                                                        float* __restrict__ sig) {
    const int wg = blockIdx.x;          // b * 2 + ch
    const int b  = wg >> 1;
    const int ch = wg & 1;
    const int s0 = ch * CH_STEPS;
    const int nst = ch ? (STEPS_TOTAL - CH_STEPS) : CH_STEPS;   // 255 : 256
    const int t = threadIdx.x;

    __shared__ __align__(8) float dxs[CH_STEPS * 8];   // 8 KB, for vj/vk reads
    const float2* __restrict__ Xg2 = (const float2*)(X + ((size_t)b * LEN + s0) * 8);
    float2* __restrict__ d2 = (float2*)dxs;
    {   // q in [0,512): always valid (reads up to X row s0+128)
        const float2 a = Xg2[t], c = Xg2[t + 4];
        d2[t] = make_float2(c.x - a.x, c.y - a.y);
    }
    {   // q in [512,1024): guard the pad region of chunk 1 (no OOB loads)
        const int q = t + 512;
        float2 r = make_float2(0.f, 0.f);
        if (q < nst * 4) {
            const float2 a = Xg2[q], c = Xg2[q + 4];
            r = make_float2(c.x - a.x, c.y - a.y);
        }
        d2[q] = r;
    }
    __syncthreads();

    const float4* __restrict__ Xf4 = (const float4*)(X + (size_t)b * LEN * 8);
    float* __restrict__ o = sig + (size_t)wg * SIG_DIM;
    if (ch == 0) scan_dispatch<CH_STEPS>(Xf4, s0, dxs, o, t);
    else         scan_dispatch<STEPS_TOTAL - CH_STEPS>(Xf4, s0, dxs, o, t);
}

// ---------------------------------------------------------------------------
// Kernel 2: ONE Chen-combine (chunk0 x chunk1) straight from global (no LDS
// staging, no barriers before the reduce) + fused linear + block reduction.
// 128 blocks x 512 threads.
// ---------------------------------------------------------------------------
__global__ __launch_bounds__(512) void sig_combine_linear(const float* __restrict__ sig,
                                                          const float* __restrict__ W,
                                                          const float* __restrict__ bias,
                                                          float* __restrict__ out) {
    const int b = blockIdx.x;
    const int t = threadIdx.x;
    const int i = t >> 6, j = (t >> 3) & 7, k = t & 7;
    const float* __restrict__ A = sig + (size_t)(b * 2) * SIG_DIM;   // chunk 0
    const float* __restrict__ B = A + SIG_DIM;                       // chunk 1

    // A := chunk 0 signature (per-thread ownership as in kernel 1)
    float A1 = A[i];
    float A2 = A[OFF2 + i * 8 + j];
    float A3 = A[OFF3 + t];
    const float4 a4a = *(const float4*)&A[OFF4 + t * 8];
    const float4 a4b = *(const float4*)&A[OFF4 + t * 8 + 4];
    float A4[8] = {a4a.x, a4a.y, a4a.z, a4a.w, a4b.x, a4b.y, a4b.z, a4b.w};

    // B values straight from global (L2-resident, 18.7 KB per block)
    const float B1i = B[i], B1j = B[j], B1k = B[k];
    const float4 b1a = *(const float4*)&B[0];
    const float4 b1b = *(const float4*)&B[4];
    const float B2ij = B[OFF2 + i * 8 + j];
    const float B2jk = B[OFF2 + j * 8 + k];
    const float4 b2a = *(const float4*)&B[OFF2 + k * 8];
    const float4 b2b = *(const float4*)&B[OFF2 + k * 8 + 4];
    const float B3ijk = B[OFF3 + t];
    const float4 b3a = *(const float4*)&B[OFF3 + (j * 8 + k) * 8];
    const float4 b3b = *(const float4*)&B[OFF3 + (j * 8 + k) * 8 + 4];
    const float4 b4a = *(const float4*)&B[OFF4 + t * 8];
    const float4 b4b = *(const float4*)&B[OFF4 + t * 8 + 4];

    // C4 = A4 + A3⊗B1 + A2⊗B2 + A1⊗B3 + B4   (old A1..A3)
    A4[0] += A3 * b1a.x + A2 * b2a.x + A1 * b3a.x + b4a.x;
    A4[1] += A3 * b1a.y + A2 * b2a.y + A1 * b3a.y + b4a.y;
    A4[2] += A3 * b1a.z + A2 * b2a.z + A1 * b3a.z + b4a.z;
    A4[3] += A3 * b1a.w + A2 * b2a.w + A1 * b3a.w + b4a.w;
    A4[4] += A3 * b1b.x + A2 * b2b.x + A1 * b3b.x + b4b.x;
    A4[5] += A3 * b1b.y + A2 * b2b.y + A1 * b3b.y + b4b.y;
    A4[6] += A3 * b1b.z + A2 * b2b.z + A1 * b3b.z + b4b.z;
    A4[7] += A3 * b1b.w + A2 * b2b.w + A1 * b3b.w + b4b.w;
    // C3 = A3 + A2⊗B1 + A1⊗B2 + B3
    A3 += A2 * B1k + A1 * B2jk + B3ijk;
    // C2 = A2 + A1⊗B1 + B2
    A2 += A1 * B1j + B2ij;
    // C1
    A1 += B1i;

    // Fused linear: out[b][n] = sum_d sig[d] * W[n][d] + bias[n]
    float part[N_OUT];
    #pragma unroll
    for (int n = 0; n < N_OUT; ++n) {
        const float* __restrict__ Wn = W + (size_t)n * SIG_DIM;
        float p = A3 * Wn[OFF3 + t];
        const float4 w4a = *(const float4*)&Wn[OFF4 + t * 8];
        const float4 w4b = *(const float4*)&Wn[OFF4 + t * 8 + 4];
        p = fmaf(A4[0], w4a.x, p);
        p = fmaf(A4[1], w4a.y, p);
        p = fmaf(A4[2], w4a.z, p);
        p = fmaf(A4[3], w4a.w, p);
        p = fmaf(A4[4], w4b.x, p);
        p = fmaf(A4[5], w4b.y, p);
        p = fmaf(A4[6], w4b.z, p);
        p = fmaf(A4[7], w4b.w, p);
        if ((t & 7) == 0)  p = fmaf(A2, Wn[OFF2 + (t >> 3)], p);  // canonical s2 owner
        if ((t & 63) == 0) p = fmaf(A1, Wn[t >> 6], p);           // canonical s1 owner
        part[n] = p;
    }

    // wave reduce (64 lanes) then cross-wave via LDS
    #pragma unroll
    for (int n = 0; n < N_OUT; ++n) {
        #pragma unroll
        for (int off = 32; off > 0; off >>= 1)
            part[n] += __shfl_xor(part[n], off, 64);
    }
    __shared__ float red[8][N_OUT];
    const int wv = t >> 6, ln = t & 63;
    if (ln == 0) {
        #pragma unroll
        for (int n = 0; n < N_OUT; ++n) red[wv][n] = part[n];
    }
    __syncthreads();
    if (t < N_OUT) {
        float s = bias[t];
        #pragma unroll
        for (int w = 0; w < 8; ++w) s += red[w][t];
        out[b * N_OUT + t] = s;
    }
}

extern "C" void kernel_launch(void* const* d_in, const int* in_sizes, int n_in,
                              void* d_out, int out_size, void* d_ws, size_t ws_size,
                              hipStream_t stream) {
    const float* X    = (const float*)d_in[0];
    const float* W    = (const float*)d_in[1];
    const float* bias = (const float*)d_in[2];
    float* out = (float*)d_out;
    float* sig = (float*)d_ws;                 // 2*BATCH*SIG_DIM*4 ≈ 4.8 MB

    hipLaunchKernelGGL(sig_chunk_kernel, dim3(BATCH * NCHUNK), dim3(512), 0, stream, X, sig);
    hipLaunchKernelGGL(sig_combine_linear, dim3(BATCH), dim3(512), 0, stream, sig, W, bias, out);
}